// Round 3
// baseline (634.456 us; speedup 1.0000x reference)
//
#include <hip/hip_runtime.h>
#include <hip/hip_bf16.h>

typedef __attribute__((ext_vector_type(8))) short short8;     // 8 x bf16 (4 VGPRs)
typedef __attribute__((ext_vector_type(4))) float floatx4;    // MFMA accumulator

static __device__ __forceinline__ unsigned f2bf(float f) {   // RNE f32->bf16 bits
    unsigned u = __builtin_bit_cast(unsigned, f);
    unsigned r = u + 0x7fffu + ((u >> 16) & 1u);
    return r >> 16;
}
static __device__ __forceinline__ unsigned pk2bf(float lo, float hi) {
    return f2bf(lo) | (f2bf(hi) << 16);
}

// ---------------------------------------------------------------------------
// Prep: T^T[d][k] (k = c*4 + rr*2 + q), u[d] = sum nw*W, v[d] = sum nb*W.
// Reference channel order is concat([ll,lh,hl,hh]) -> channel s*96+c.
// T[(c,rr,q)][d] = 0.5 * sum_s sign(s,(rr,q)) * nw[s*96+c] * W[s*96+c][d]
// All inputs FLOAT32; Tt emitted as bf16 for the MFMA.
// ---------------------------------------------------------------------------
__global__ __launch_bounds__(384)
void prep_kernel(const float* __restrict__ nw,
                 const float* __restrict__ nb,
                 const float* __restrict__ W,    // [384][192] f32
                 __hip_bfloat16* __restrict__ Tt, // [192][384] bf16
                 float* __restrict__ uvec,
                 float* __restrict__ vvec)
{
    __shared__ float su[384];
    __shared__ float sv[384];
    const int d = blockIdx.x;     // 0..191
    const int t = threadIdx.x;    // 0..383

    const int c  = t >> 2;
    const int rr = (t >> 1) & 1;
    const int q  = t & 1;

    float w0 = W[(0 * 96 + c) * 192 + d];  // ll
    float w1 = W[(1 * 96 + c) * 192 + d];  // lh
    float w2 = W[(2 * 96 + c) * 192 + d];  // hl
    float w3 = W[(3 * 96 + c) * 192 + d];  // hh
    float n0 = nw[0 * 96 + c];
    float n1 = nw[1 * 96 + c];
    float n2 = nw[2 * 96 + c];
    float n3 = nw[3 * 96 + c];

    float slh = rr ? -1.f : 1.f;
    float shl = q  ? -1.f : 1.f;
    float shh = (rr ^ q) ? -1.f : 1.f;
    float tv = 0.5f * (n0 * w0 + slh * n1 * w1 + shl * n2 * w2 + shh * n3 * w3);
    ((unsigned short*)Tt)[d * 384 + t] = (unsigned short)f2bf(tv);

    float wt = W[t * 192 + d];
    su[t] = nw[t] * wt;
    sv[t] = nb[t] * wt;
    __syncthreads();
    if (t < 64) {
        float a = su[t] + su[t + 64] + su[t + 128] + su[t + 192] + su[t + 256] + su[t + 320];
        float b = sv[t] + sv[t + 64] + sv[t + 128] + sv[t + 192] + sv[t + 256] + sv[t + 320];
        for (int off = 32; off; off >>= 1) {
            a += __shfl_down(a, off);
            b += __shfl_down(b, off);
        }
        if (t == 0) { uvec[d] = a; vvec[d] = b; }
    }
}

// ---------------------------------------------------------------------------
// Main fused kernel. Block: 256 thr (4 waves), tile M=64 positions x N=192.
// x is FLOAT32. Stage x tile (f32 -> bf16 RNE) into LDS As[m][k], pitch 392
// (784 B rows = 49*16B, aligned); LN stats in f32 during staging
// (sum_k y = 2*sum_c a_c; sum_k y^2 = sum x^2 — Haar is orthonormal per block).
// GEMM swapped operands: A = Tt rows (d), B = As rows (positions);
// C[d][pos]: lane holds 4 consecutive d for one pos -> float4 stores.
// ---------------------------------------------------------------------------
__global__ __launch_bounds__(256, 2)
void fused_kernel(const float* __restrict__ x,
                  const __hip_bfloat16* __restrict__ Tt,
                  const float* __restrict__ uvec,
                  const float* __restrict__ vvec,
                  float* __restrict__ out)
{
    constexpr int PK = 392;
    __shared__ __align__(16) __hip_bfloat16 As[64 * PK];  // 50176 B
    __shared__ float S1p[256];
    __shared__ float S2p[256];
    __shared__ float2 ab[64];

    const int t  = threadIdx.x;
    const int bi = blockIdx.x;
    const int mb = bi & 1;          // half of the w-row
    const int h  = (bi >> 1) & 127; // output row (half-res)
    const int b  = bi >> 8;         // batch

    // ---- stage x tile into LDS (bf16) + LN stats (f32) ----
    {
        const int m  = t & 63;   // position within tile (w_half = mb*64+m)
        const int cg = t >> 6;   // channel group (0..3), 24 channels each
        const float2* xrow =
            (const float2*)(x + ((size_t)b * 96 * 65536 + (size_t)(2 * h) * 256))
            + (mb * 64 + m);
        float s1 = 0.f, s2 = 0.f;
#pragma unroll
        for (int i = 0; i < 24; ++i) {
            const int ch = cg * 24 + i;
            const float2* p = xrow + (size_t)ch * 32768;  // ch * 65536 elems
            float2 tp = p[0];     // row 2h   : (a, b)
            float2 bt = p[128];   // row 2h+1 : (c, d)
            s1 += tp.x;                                        // sum_k y = 2*s1
            s2 += tp.x * tp.x + tp.y * tp.y + bt.x * bt.x + bt.y * bt.y;
            *(uint2*)(&As[m * PK + ch * 4]) =
                make_uint2(pk2bf(tp.x, tp.y), pk2bf(bt.x, bt.y));
        }
        S1p[t] = s1;
        S2p[t] = s2;
    }
    __syncthreads();
    if (t < 64) {
        float S1 = S1p[t] + S1p[t + 64] + S1p[t + 128] + S1p[t + 192];
        float S2 = S2p[t] + S2p[t + 64] + S2p[t + 128] + S2p[t + 192];
        float mu  = S1 * (2.0f / 384.0f);
        float var = S2 * (1.0f / 384.0f) - mu * mu;
        float rs  = rsqrtf(var + 1e-5f);
        ab[t] = make_float2(rs, -rs * mu);
    }
    __syncthreads();

    // ---- GEMM: per wave 3 d-tiles (48 cols of d) x 4 pos-tiles ----
    const int lane = t & 63;
    const int wv   = t >> 6;
    const int l15  = lane & 15;
    const int q2   = lane >> 4;   // 0..3

    const short8* Ap0 = (const short8*)(Tt + (size_t)(wv * 48 + l15) * 384 + q2 * 8);
    const short8* Bp0 = (const short8*)(&As[l15 * PK + q2 * 8]);
    // strides in short8 units: A: dt -> 16*384/8 = 768, ks -> 4
    //                          B: p  -> 16*392/8 = 784, ks -> 4

    floatx4 acc[3][4];
#pragma unroll
    for (int dt = 0; dt < 3; ++dt)
#pragma unroll
        for (int p = 0; p < 4; ++p)
            acc[dt][p] = (floatx4){0.f, 0.f, 0.f, 0.f};

#pragma unroll 2
    for (int ks = 0; ks < 12; ++ks) {
        short8 af[3], bf[4];
#pragma unroll
        for (int dt = 0; dt < 3; ++dt) af[dt] = Ap0[dt * 768 + ks * 4];
#pragma unroll
        for (int p = 0; p < 4; ++p) bf[p] = Bp0[p * 784 + ks * 4];
#pragma unroll
        for (int dt = 0; dt < 3; ++dt)
#pragma unroll
            for (int p = 0; p < 4; ++p)
                acc[dt][p] = __builtin_amdgcn_mfma_f32_16x16x32_bf16(
                    af[dt], bf[p], acc[dt][p], 0, 0, 0);
    }

    // ---- epilogue: C[d][pos] -> out[b][l][d] (f32), float4 per lane ----
    float2 abv[4];
#pragma unroll
    for (int p = 0; p < 4; ++p) abv[p] = ab[p * 16 + l15];

    const size_t outbase = ((size_t)b * 16384 + (size_t)h * 128 + mb * 64) * 192;
#pragma unroll
    for (int dt = 0; dt < 3; ++dt) {
        const int drow = wv * 48 + dt * 16 + q2 * 4;
        floatx4 uu = *(const floatx4*)(uvec + drow);
        floatx4 vv = *(const floatx4*)(vvec + drow);
#pragma unroll
        for (int p = 0; p < 4; ++p) {
            const int pos = p * 16 + l15;
            const float al = abv[p].x, be = abv[p].y;
            floatx4 o;
            o[0] = al * acc[dt][p][0] + be * uu[0] + vv[0];
            o[1] = al * acc[dt][p][1] + be * uu[1] + vv[1];
            o[2] = al * acc[dt][p][2] + be * uu[2] + vv[2];
            o[3] = al * acc[dt][p][3] + be * uu[3] + vv[3];
            *(floatx4*)(out + outbase + (size_t)pos * 192 + drow) = o;
        }
    }
}

// ---------------------------------------------------------------------------
extern "C" void kernel_launch(void* const* d_in, const int* in_sizes, int n_in,
                              void* d_out, int out_size, void* d_ws, size_t ws_size,
                              hipStream_t stream)
{
    const float* x  = (const float*)d_in[0];
    const float* nw = (const float*)d_in[1];
    const float* nb = (const float*)d_in[2];
    const float* W  = (const float*)d_in[3];
    float* out = (float*)d_out;

    __hip_bfloat16* Tt = (__hip_bfloat16*)d_ws;                 // 192*384 bf16
    float* uvec = (float*)((char*)d_ws + 384 * 192 * 2);        // 192 f32
    float* vvec = uvec + 192;                                   // 192 f32

    prep_kernel<<<192, 384, 0, stream>>>(nw, nb, W, Tt, uvec, vvec);
    fused_kernel<<<4096, 256, 0, stream>>>(x, Tt, uvec, vvec, out);
}